// Round 5
// baseline (934.197 us; speedup 1.0000x reference)
//
#include <hip/hip_runtime.h>
#include <hip/hip_bf16.h>

#define N_NODES 100000
#define N_EDGES 1600000
#define BN_EPS 1e-5f

typedef __hip_bfloat16 bf16;
typedef float v2f __attribute__((ext_vector_type(2)));

__device__ __forceinline__ float b2f(bf16 v) { return __bfloat162float(v); }
__device__ __forceinline__ float frcp(float x) { return __builtin_amdgcn_rcpf(x); }
__device__ __forceinline__ float fsig(float x) { return frcp(1.0f + __expf(-x)); }
__device__ __forceinline__ float ftanh(float x) {
    return 1.0f - 2.0f * frcp(__expf(2.0f * x) + 1.0f);
}
__device__ __forceinline__ float bfr(uint u) { return __uint_as_float(u << 16); }

// ---- utility ---------------------------------------------------------------
__global__ void k_zero_f(float* __restrict__ p, int n) {
    int i = blockIdx.x * 256 + threadIdx.x;
    if (i < n) p[i] = 0.f;
}
__global__ void k_marker(float* __restrict__ p, int n, float v) {
    int i = blockIdx.x * 256 + threadIdx.x;
    if (i < n) p[i] = v;
}

// ---- histogram: cnt[dst]++, deg[dst] += ew ---------------------------------
__global__ void k_hist(const int* __restrict__ ei, const float* __restrict__ ew,
                       int* __restrict__ cnt, float* __restrict__ deg) {
    int e = blockIdx.x * 256 + threadIdx.x;
    if (e < N_EDGES) {
        int d = ei[N_EDGES + e];
        atomicAdd(&cnt[d], 1);
        atomicAdd(&deg[d], ew[e]);
    }
}

// ---- single-block exclusive scan: cnt -> off, cursor; off[N]=E -------------
__global__ __launch_bounds__(1024) void k_scan(const int* __restrict__ cnt,
                                               int* __restrict__ off,
                                               int* __restrict__ cursor) {
    __shared__ int tsum[1024];
    int t = threadIdx.x;
    const int per = (N_NODES + 1023) / 1024;   // 98
    int base = t * per;
    int s = 0;
    for (int i = 0; i < per; i++) {
        int idx = base + i;
        if (idx < N_NODES) s += cnt[idx];
    }
    tsum[t] = s; __syncthreads();
    for (int st = 1; st < 1024; st <<= 1) {
        int v = (t >= st) ? tsum[t - st] : 0;
        __syncthreads();
        tsum[t] += v;
        __syncthreads();
    }
    int run = (t == 0) ? 0 : tsum[t - 1];
    for (int i = 0; i < per; i++) {
        int idx = base + i;
        if (idx < N_NODES) { off[idx] = run; cursor[idx] = run; run += cnt[idx]; }
    }
    if (t == 1023) off[N_NODES] = run;
}

// ---- scatter edges into CSR slots as {src, norm} ---------------------------
__global__ void k_scatter(const int* __restrict__ ei, const float* __restrict__ ew,
                          const float* __restrict__ deg, int* __restrict__ cursor,
                          int2* __restrict__ epk) {
    int e = blockIdx.x * 256 + threadIdx.x;
    if (e < N_EDGES) {
        int s = ei[e], d = ei[N_EDGES + e];
        float nm = ew[e] * rsqrtf((deg[s] + 1.0f) * (deg[d] + 1.0f));
        int pos = atomicAdd(&cursor[d], 1);
        epk[pos] = make_int2(s, __float_as_int(nm));
    }
}

// ---- column sums of x (for skip_avg) ---------------------------------------
__global__ void k_xmean(const float* __restrict__ x, float* __restrict__ xsum) {
    __shared__ float s[256];
    int f = threadIdx.x & 31, rg = threadIdx.x >> 5;
    float acc = 0.f;
    for (int n = blockIdx.x * 8 + rg; n < N_NODES; n += gridDim.x * 8)
        acc += x[n * 32 + f];
    s[threadIdx.x] = acc; __syncthreads();
    for (int st = 128; st >= 32; st >>= 1) {
        if (threadIdx.x < st) s[threadIdx.x] += s[threadIdx.x + st];
        __syncthreads();
    }
    if (threadIdx.x < 32) atomicAdd(&xsum[threadIdx.x], s[threadIdx.x]);
}

// ---- A = x @ W1 (fp32 in, bf16 out) ----------------------------------------
__global__ void k_xw1(const float* __restrict__ x, const float* __restrict__ w,
                      bf16* __restrict__ A) {
    __shared__ float Ws[32 * 33];
    __shared__ float xs[256];
    for (int i = threadIdx.x; i < 1024; i += 256)
        Ws[(i >> 5) * 33 + (i & 31)] = w[i];
    long base = (long)blockIdx.x * 256;
    xs[threadIdx.x] = x[base + threadIdx.x];
    __syncthreads();
    int r = threadIdx.x >> 5, h = threadIdx.x & 31;
    float acc = 0.f;
#pragma unroll
    for (int f = 0; f < 32; f++) acc += xs[r * 32 + f] * Ws[f * 33 + h];
    A[base + threadIdx.x] = __float2bfloat16(acc);
}

// ---- pull-mode GCN: agg + self-loop + bias + relu + BN stats ---------------
__global__ __launch_bounds__(256) void k_gcn(
    const int* __restrict__ off, const int2* __restrict__ epk,
    const bf16* __restrict__ A, const float* __restrict__ deg,
    const float* __restrict__ bias, bf16* __restrict__ B,
    float* __restrict__ sum, float* __restrict__ sq) {
    __shared__ float s1[256], s2[256];
    const ushort* Au = (const ushort*)A;
    int tid = threadIdx.x, f = tid & 31, g = tid >> 5;
    float bv = bias[f];
    float a1 = 0.f, a2 = 0.f;
    for (int n = blockIdx.x * 8 + g; n < N_NODES; n += gridDim.x * 8) {
        int lo = off[n], hi = off[n + 1];
        float acc0 = 0.f, acc1 = 0.f;
        int p = lo;
        for (; p + 1 < hi; p += 2) {
            int2 e0 = epk[p], e1 = epk[p + 1];
            acc0 += bfr(Au[(long)e0.x * 32 + f]) * __int_as_float(e0.y);
            acc1 += bfr(Au[(long)e1.x * 32 + f]) * __int_as_float(e1.y);
        }
        if (p < hi) {
            int2 e0 = epk[p];
            acc0 += bfr(Au[(long)e0.x * 32 + f]) * __int_as_float(e0.y);
        }
        float self = bfr(Au[(long)n * 32 + f]) / (deg[n] + 1.0f);
        float v = fmaxf(acc0 + acc1 + self + bv, 0.f);
        B[(long)n * 32 + f] = __float2bfloat16(v);
        a1 += v; a2 += v * v;
    }
    s1[tid] = a1; s2[tid] = a2; __syncthreads();
    for (int st = 128; st >= 32; st >>= 1) {
        if (tid < st) { s1[tid] += s1[tid + st]; s2[tid] += s2[tid + st]; }
        __syncthreads();
    }
    if (tid < 32) { atomicAdd(&sum[f], s1[f]); atomicAdd(&sq[f], s2[f]); }
}

// ---- BN1 finalize ----------------------------------------------------------
__global__ void k_fin1(const float* __restrict__ sum, const float* __restrict__ sq,
                       const float* __restrict__ g, const float* __restrict__ be,
                       float* __restrict__ scale, float* __restrict__ shift) {
    int t = threadIdx.x;
    if (t < 32) {
        float mu = sum[t] / (float)N_NODES;
        float var = sq[t] / (float)N_NODES - mu * mu;
        float rs = rsqrtf(var + BN_EPS) * g[t];
        scale[t] = rs;
        shift[t] = be[t] - mu * rs;
    }
}

// ---- H = affine(B) (bf16); A = H @ W2 (bf16) -------------------------------
__global__ void k_aff_xw(const bf16* __restrict__ B, const float* __restrict__ scale,
                         const float* __restrict__ shift, const float* __restrict__ w,
                         bf16* __restrict__ H, bf16* __restrict__ A) {
    __shared__ float Ws[32 * 33];
    __shared__ float hs[256];
    for (int i = threadIdx.x; i < 1024; i += 256)
        Ws[(i >> 5) * 33 + (i & 31)] = w[i];
    long base = (long)blockIdx.x * 256;
    int f = threadIdx.x & 31;
    float h = b2f(B[base + threadIdx.x]) * scale[f] + shift[f];
    H[base + threadIdx.x] = __float2bfloat16(h);
    hs[threadIdx.x] = h;
    __syncthreads();
    int r = threadIdx.x >> 5, hc = threadIdx.x & 31;
    float acc = 0.f;
#pragma unroll
    for (int k = 0; k < 32; k++) acc += hs[r * 32 + k] * Ws[k * 33 + hc];
    A[base + threadIdx.x] = __float2bfloat16(acc);
}

// ---- BN2 finalize + fc1 const + combined LSTM biases -----------------------
__global__ void k_fin2(const float* __restrict__ sum, const float* __restrict__ sq,
                       const float* __restrict__ g, const float* __restrict__ be,
                       const float* __restrict__ xsum, const float* __restrict__ fw1,
                       const float* __restrict__ fb1,
                       const float* __restrict__ bih1, const float* __restrict__ bhh1,
                       const float* __restrict__ bih2, const float* __restrict__ bhh2,
                       float* __restrict__ scale, float* __restrict__ shift,
                       float* __restrict__ fc1c, float* __restrict__ lb1,
                       float* __restrict__ lb2) {
    int t = threadIdx.x;
    if (t < 32) {
        float mu = sum[t] / (float)N_NODES;
        float var = sq[t] / (float)N_NODES - mu * mu;
        float rs = rsqrtf(var + BN_EPS) * g[t];
        scale[t] = rs;
        shift[t] = be[t] - mu * rs;
        float c = fb1[t];
        for (int f = 0; f < 32; f++)
            c += (xsum[f] / (float)N_NODES) * fw1[t * 96 + 64 + f];
        fc1c[t] = c;
    }
    if (t < 128) {
        lb1[t] = bih1[t] + bhh1[t];
        lb2[t] = bih2[t] + bhh2[t];
    }
}

// ---- per-node dense stack: LDS-broadcast weights + v_pk_fma ---------------
// One thread per node. All lanes read identical LDS addresses (broadcast).
// PyTorch gate order i,f,g,o; f-gate dead (c0=0 => c = sig(i)*tanh(g)).
__global__ __launch_bounds__(128) void k_final(
    const bf16* __restrict__ Hb, const bf16* __restrict__ Bb,
    const float* __restrict__ scale2, const float* __restrict__ shift2,
    const float* __restrict__ wih1, const float* __restrict__ wih2,
    const float* __restrict__ fw1, const float* __restrict__ fw2,
    const float* __restrict__ fb2,
    const float* __restrict__ fc1c, const float* __restrict__ lb1,
    const float* __restrict__ lb2, float* __restrict__ out) {
    __shared__ float4 Wa[1536];   // LSTM1: i rows 0..511, g 512..1023, o 1024..1535
    __shared__ float4 Wb[768];    // LSTM2: i/g/o, 8 float4 per row
    __shared__ float4 Fc[512];    // fc1 rows j: k 0..63 (16 float4)
    __shared__ float lb1s[128], lb2s[128], fc1s[32], fw2s[32], sc2[32], sh2[32];
    int tid = threadIdx.x;
    for (int i = tid; i < 1536; i += 128) {
        int t = i >> 9, rem = i & 511, c = rem >> 4, q = rem & 15;
        int row = (t == 0) ? c : ((t == 1) ? c + 64 : c + 96);
        Wa[i] = ((const float4*)(wih1 + row * 64))[q];
    }
    for (int i = tid; i < 768; i += 128) {
        int t = i / 256, rem = i % 256, c = rem >> 3, q = rem & 7;
        int row = (t == 0) ? c : ((t == 1) ? c + 64 : c + 96);
        Wb[i] = ((const float4*)(wih2 + row * 32))[q];
    }
    for (int i = tid; i < 512; i += 128) {
        int j = i >> 4, q = i & 15;
        Fc[i] = ((const float4*)(fw1 + j * 96))[q];
    }
    if (tid < 128) { lb1s[tid] = lb1[tid]; lb2s[tid] = lb2[tid]; }
    if (tid < 32) {
        fc1s[tid] = fc1c[tid]; fw2s[tid] = fw2[tid];
        sc2[tid] = scale2[tid]; sh2[tid] = shift2[tid];
    }
    __syncthreads();
    int n = blockIdx.x * 128 + tid;
    if (n >= N_NODES) return;

    v2f cat2[32];
    const uint4* Hv = (const uint4*)((const ushort*)Hb + (long)n * 32);
    const uint4* Bv = (const uint4*)((const ushort*)Bb + (long)n * 32);
#pragma unroll
    for (int q = 0; q < 4; q++) {
        uint4 hu = Hv[q], bu = Bv[q];
        uint hw[4] = {hu.x, hu.y, hu.z, hu.w};
        uint bw[4] = {bu.x, bu.y, bu.z, bu.w};
#pragma unroll
        for (int r = 0; r < 4; r++) {
            int u = q * 4 + r;           // uint index: elements 2u, 2u+1
            float h0 = __uint_as_float(hw[r] << 16);
            float h1 = __uint_as_float(hw[r] & 0xffff0000u);
            cat2[u] = (v2f){h0, h1};
            float b0 = __uint_as_float(bw[r] << 16);
            float b1 = __uint_as_float(bw[r] & 0xffff0000u);
            int e0 = 2 * u, e1 = 2 * u + 1;
            cat2[16 + u] = (v2f){b0 * sc2[e0] + sh2[e0], b1 * sc2[e1] + sh2[e1]};
        }
    }
    v2f hn1v[16];
#pragma unroll
    for (int c = 0; c < 32; c++) {
        v2f ai = (v2f)0.f, ag = (v2f)0.f, ao = (v2f)0.f;
#pragma unroll
        for (int q = 0; q < 16; q++) {
            float4 wi = Wa[c * 16 + q], wg = Wa[512 + c * 16 + q], wo = Wa[1024 + c * 16 + q];
            v2f x0 = cat2[2 * q], x1 = cat2[2 * q + 1];
            ai = __builtin_elementwise_fma((v2f){wi.x, wi.y}, x0, ai);
            ai = __builtin_elementwise_fma((v2f){wi.z, wi.w}, x1, ai);
            ag = __builtin_elementwise_fma((v2f){wg.x, wg.y}, x0, ag);
            ag = __builtin_elementwise_fma((v2f){wg.z, wg.w}, x1, ag);
            ao = __builtin_elementwise_fma((v2f){wo.x, wo.y}, x0, ao);
            ao = __builtin_elementwise_fma((v2f){wo.z, wo.w}, x1, ao);
        }
        float gi = ai.x + ai.y + lb1s[c];
        float gg = ag.x + ag.y + lb1s[64 + c];
        float go = ao.x + ao.y + lb1s[96 + c];
        float c1 = fsig(gi) * ftanh(gg);
        hn1v[c >> 1][c & 1] = fsig(go) * ftanh(c1);
    }
    v2f hn2v[16];
#pragma unroll
    for (int c = 0; c < 32; c++) {
        v2f ai = (v2f)0.f, ag = (v2f)0.f, ao = (v2f)0.f;
#pragma unroll
        for (int q = 0; q < 8; q++) {
            float4 wi = Wb[c * 8 + q], wg = Wb[256 + c * 8 + q], wo = Wb[512 + c * 8 + q];
            v2f x0 = hn1v[2 * q], x1 = hn1v[2 * q + 1];
            ai = __builtin_elementwise_fma((v2f){wi.x, wi.y}, x0, ai);
            ai = __builtin_elementwise_fma((v2f){wi.z, wi.w}, x1, ai);
            ag = __builtin_elementwise_fma((v2f){wg.x, wg.y}, x0, ag);
            ag = __builtin_elementwise_fma((v2f){wg.z, wg.w}, x1, ag);
            ao = __builtin_elementwise_fma((v2f){wo.x, wo.y}, x0, ao);
            ao = __builtin_elementwise_fma((v2f){wo.z, wo.w}, x1, ao);
        }
        float gi = ai.x + ai.y + lb2s[c];
        float gg = ag.x + ag.y + lb2s[64 + c];
        float go = ao.x + ao.y + lb2s[96 + c];
        float c2 = fsig(gi) * ftanh(gg);
        hn2v[c >> 1][c & 1] = fsig(go) * ftanh(c2);
    }
    float acc = fb2[0];
#pragma unroll
    for (int j = 0; j < 32; j++) {
        v2f z2 = (v2f)0.f;
#pragma unroll
        for (int q = 0; q < 8; q++) {
            float4 w = Fc[j * 16 + q];
            z2 = __builtin_elementwise_fma((v2f){w.x, w.y}, hn1v[2 * q], z2);
            z2 = __builtin_elementwise_fma((v2f){w.z, w.w}, hn1v[2 * q + 1], z2);
        }
#pragma unroll
        for (int q = 0; q < 8; q++) {
            float4 w = Fc[j * 16 + 8 + q];
            z2 = __builtin_elementwise_fma((v2f){w.x, w.y}, hn2v[2 * q], z2);
            z2 = __builtin_elementwise_fma((v2f){w.z, w.w}, hn2v[2 * q + 1], z2);
        }
        float z = z2.x + z2.y + fc1s[j];
        acc += fmaxf(z, 0.f) * fw2s[j];
    }
    out[n] = acc;
}

extern "C" void kernel_launch(void* const* d_in, const int* in_sizes, int n_in,
                              void* d_out, int out_size, void* d_ws, size_t ws_size,
                              hipStream_t stream) {
    const float* x    = (const float*)d_in[0];
    const int*   ei   = (const int*)d_in[1];
    const float* ew   = (const float*)d_in[2];
    const float* w1   = (const float*)d_in[3];
    const float* b1   = (const float*)d_in[4];
    const float* g1   = (const float*)d_in[5];
    const float* be1  = (const float*)d_in[6];
    const float* w2   = (const float*)d_in[7];
    const float* b2   = (const float*)d_in[8];
    const float* g2   = (const float*)d_in[9];
    const float* be2  = (const float*)d_in[10];
    const float* wih1 = (const float*)d_in[11];
    const float* bih1 = (const float*)d_in[13];
    const float* bhh1 = (const float*)d_in[14];
    const float* wih2 = (const float*)d_in[15];
    const float* bih2 = (const float*)d_in[17];
    const float* bhh2 = (const float*)d_in[18];
    const float* fw1  = (const float*)d_in[19];
    const float* fb1  = (const float*)d_in[20];
    const float* fw2  = (const float*)d_in[21];
    const float* fb2  = (const float*)d_in[22];
    float* out = (float*)d_out;

    // ---- workspace layout (34.1 MB; known-good ws >= 41.1 MB) --------------
    char* ws = (char*)d_ws;
    float* stats = (float*)ws;                          // 576 floats @ 0
    float* xsum   = stats + 0;
    float* bn1sum = stats + 32;
    float* bn1sq  = stats + 64;
    float* bn2sum = stats + 96;
    float* bn2sq  = stats + 128;
    float* scale1 = stats + 160;
    float* shift1 = stats + 192;
    float* scale2 = stats + 224;
    float* shift2 = stats + 256;
    float* fc1c   = stats + 288;
    float* lb1    = stats + 320;
    float* lb2    = stats + 448;
    float* deg   = (float*)(ws + 4096);                 // 100000 f -> 404,096
    int*   cnt   = (int*)  (ws + 404096);               // 100000 i -> 804,096
    int*   off   = (int*)  (ws + 1048576);              // 100001 i
    int*   cursor= (int*)  (ws + 1572864);              // 100000 i
    int2*  epk   = (int2*) (ws + 2097152);              // 1.6M int2 -> 14,897,152
    bf16*  A     = (bf16*) (ws + 14897152);             // 6.4MB -> 21,297,152
    bf16*  H     = (bf16*) (ws + 21297152);             // 6.4MB -> 27,697,152
    bf16*  B     = (bf16*) (ws + 27697152);             // 6.4MB -> 34,097,152

    if (ws_size < 34200000ull) {
        k_marker<<<(N_NODES + 255) / 256, 256, 0, stream>>>(out, N_NODES, 911.f);
        return;
    }

    // zero stats+deg+cnt in one shot (contiguous words 0 .. 804,096 bytes)
    k_zero_f<<<786, 256, 0, stream>>>(stats, 201024);

    k_hist<<<6250, 256, 0, stream>>>(ei, ew, cnt, deg);
    k_scan<<<1, 1024, 0, stream>>>(cnt, off, cursor);
    k_scatter<<<6250, 256, 0, stream>>>(ei, ew, deg, cursor, epk);
    k_xmean<<<400, 256, 0, stream>>>(x, xsum);
    k_xw1<<<12500, 256, 0, stream>>>(x, w1, A);
    k_gcn<<<1024, 256, 0, stream>>>(off, epk, A, deg, b1, B, bn1sum, bn1sq);
    k_fin1<<<1, 64, 0, stream>>>(bn1sum, bn1sq, g1, be1, scale1, shift1);
    k_aff_xw<<<12500, 256, 0, stream>>>(B, scale1, shift1, w2, H, A);
    k_gcn<<<1024, 256, 0, stream>>>(off, epk, A, deg, b2, B, bn2sum, bn2sq);
    k_fin2<<<1, 128, 0, stream>>>(bn2sum, bn2sq, g2, be2, xsum, fw1, fb1,
                                  bih1, bhh1, bih2, bhh2,
                                  scale2, shift2, fc1c, lb1, lb2);
    k_final<<<782, 128, 0, stream>>>(H, B, scale2, shift2, wih1, wih2, fw1, fw2,
                                     fb2, fc1c, lb1, lb2, out);
}

// Round 7
// 679.582 us; speedup vs baseline: 1.3747x; 1.3747x over previous
//
#include <hip/hip_runtime.h>
#include <hip/hip_bf16.h>

#define N_NODES 100000
#define N_EDGES 1600000
#define BN_EPS 1e-5f
#define SCAN_BLOCKS 391   // ceil(100000/256)

typedef __hip_bfloat16 bf16;
typedef float v2f __attribute__((ext_vector_type(2)));

__device__ __forceinline__ float b2f(bf16 v) { return __bfloat162float(v); }
__device__ __forceinline__ float frcp(float x) { return __builtin_amdgcn_rcpf(x); }
__device__ __forceinline__ float fsig(float x) { return frcp(1.0f + __expf(-x)); }
__device__ __forceinline__ float ftanh(float x) {
    return 1.0f - 2.0f * frcp(__expf(2.0f * x) + 1.0f);
}
__device__ __forceinline__ float bfr(uint u) { return __uint_as_float(u << 16); }

// ---- utility ---------------------------------------------------------------
__global__ void k_zero_f(float* __restrict__ p, int n) {
    int i = blockIdx.x * 256 + threadIdx.x;
    if (i < n) p[i] = 0.f;
}
__global__ void k_marker(float* __restrict__ p, int n, float v) {
    int i = blockIdx.x * 256 + threadIdx.x;
    if (i < n) p[i] = v;
}

// ---- histogram: cnt[dst]++, deg[dst] += ew ---------------------------------
__global__ void k_hist(const int* __restrict__ ei, const float* __restrict__ ew,
                       int* __restrict__ cnt, float* __restrict__ deg) {
    int e = blockIdx.x * 256 + threadIdx.x;
    if (e < N_EDGES) {
        int d = ei[N_EDGES + e];
        atomicAdd(&cnt[d], 1);
        atomicAdd(&deg[d], ew[e]);
    }
}

// ---- parallel scan, stage 1: per-block sums --------------------------------
__global__ void k_bsum(const int* __restrict__ cnt, int* __restrict__ bsum) {
    __shared__ int s[256];
    int idx = blockIdx.x * 256 + threadIdx.x;
    s[threadIdx.x] = (idx < N_NODES) ? cnt[idx] : 0;
    __syncthreads();
    for (int st = 128; st >= 1; st >>= 1) {
        if (threadIdx.x < st) s[threadIdx.x] += s[threadIdx.x + st];
        __syncthreads();
    }
    if (threadIdx.x == 0) bsum[blockIdx.x] = s[0];
}

// ---- stage 2: exclusive scan of 391 block sums (single tiny block) ---------
__global__ __launch_bounds__(512) void k_bscan(const int* __restrict__ bsum,
                                               int* __restrict__ bbase) {
    __shared__ int s[512];
    int t = threadIdx.x;
    int v = (t < SCAN_BLOCKS) ? bsum[t] : 0;
    s[t] = v; __syncthreads();
    for (int st = 1; st < 512; st <<= 1) {
        int u = (t >= st) ? s[t - st] : 0;
        __syncthreads();
        s[t] += u;
        __syncthreads();
    }
    if (t < SCAN_BLOCKS) bbase[t] = s[t] - v;   // exclusive prefix
}

// ---- stage 3: block-local scan (wave shfl) + base -> off, cursor -----------
__global__ void k_scan3(const int* __restrict__ cnt, const int* __restrict__ bbase,
                        int* __restrict__ off, int* __restrict__ cursor) {
    __shared__ int wsum[4];
    int idx = blockIdx.x * 256 + threadIdx.x;
    int lane = threadIdx.x & 63, w = threadIdx.x >> 6;
    int c = (idx < N_NODES) ? cnt[idx] : 0;
    int s = c;
    for (int d = 1; d < 64; d <<= 1) {
        int u = __shfl_up(s, d, 64);
        if (lane >= d) s += u;
    }
    if (lane == 63) wsum[w] = s;
    __syncthreads();
    int wb = 0;
    for (int i = 0; i < w; i++) wb += wsum[i];
    int e = bbase[blockIdx.x] + wb + s - c;      // exclusive
    if (idx < N_NODES) { off[idx] = e; cursor[idx] = e; }
    if (idx == 0) off[N_NODES] = N_EDGES;        // all dst are in-range
}

// ---- scatter edges into CSR slots as {src, norm} ---------------------------
__global__ void k_scatter(const int* __restrict__ ei, const float* __restrict__ ew,
                          const float* __restrict__ deg, int* __restrict__ cursor,
                          int2* __restrict__ epk) {
    int e = blockIdx.x * 256 + threadIdx.x;
    if (e < N_EDGES) {
        int s = ei[e], d = ei[N_EDGES + e];
        float nm = ew[e] * rsqrtf((deg[s] + 1.0f) * (deg[d] + 1.0f));
        int pos = atomicAdd(&cursor[d], 1);
        epk[pos] = make_int2(s, __float_as_int(nm));
    }
}

// ---- column sums of x (for skip_avg) ---------------------------------------
__global__ void k_xmean(const float* __restrict__ x, float* __restrict__ xsum) {
    __shared__ float s[256];
    int f = threadIdx.x & 31, rg = threadIdx.x >> 5;
    float acc = 0.f;
    for (int n = blockIdx.x * 8 + rg; n < N_NODES; n += gridDim.x * 8)
        acc += x[n * 32 + f];
    s[threadIdx.x] = acc; __syncthreads();
    for (int st = 128; st >= 32; st >>= 1) {
        if (threadIdx.x < st) s[threadIdx.x] += s[threadIdx.x + st];
        __syncthreads();
    }
    if (threadIdx.x < 32) atomicAdd(&xsum[threadIdx.x], s[threadIdx.x]);
}

// ---- A = x @ W1 (fp32 in, bf16 out) ----------------------------------------
__global__ void k_xw1(const float* __restrict__ x, const float* __restrict__ w,
                      bf16* __restrict__ A) {
    __shared__ float Ws[32 * 33];
    __shared__ float xs[256];
    for (int i = threadIdx.x; i < 1024; i += 256)
        Ws[(i >> 5) * 33 + (i & 31)] = w[i];
    long base = (long)blockIdx.x * 256;
    xs[threadIdx.x] = x[base + threadIdx.x];
    __syncthreads();
    int r = threadIdx.x >> 5, h = threadIdx.x & 31;
    float acc = 0.f;
#pragma unroll
    for (int f = 0; f < 32; f++) acc += xs[r * 32 + f] * Ws[f * 33 + h];
    A[base + threadIdx.x] = __float2bfloat16(acc);
}

// ---- pull-mode GCN: agg + self-loop + bias + relu + BN stats ---------------
__global__ __launch_bounds__(256) void k_gcn(
    const int* __restrict__ off, const int2* __restrict__ epk,
    const bf16* __restrict__ A, const float* __restrict__ deg,
    const float* __restrict__ bias, bf16* __restrict__ B,
    float* __restrict__ sum, float* __restrict__ sq) {
    __shared__ float s1[256], s2[256];
    const ushort* Au = (const ushort*)A;
    int tid = threadIdx.x, f = tid & 31, g = tid >> 5;
    float bv = bias[f];
    float a1 = 0.f, a2 = 0.f;
    for (int n = blockIdx.x * 8 + g; n < N_NODES; n += gridDim.x * 8) {
        int lo = off[n], hi = off[n + 1];
        float acc0 = 0.f, acc1 = 0.f;
        int p = lo;
        for (; p + 1 < hi; p += 2) {
            int2 e0 = epk[p], e1 = epk[p + 1];
            acc0 += bfr(Au[(long)e0.x * 32 + f]) * __int_as_float(e0.y);
            acc1 += bfr(Au[(long)e1.x * 32 + f]) * __int_as_float(e1.y);
        }
        if (p < hi) {
            int2 e0 = epk[p];
            acc0 += bfr(Au[(long)e0.x * 32 + f]) * __int_as_float(e0.y);
        }
        float self = bfr(Au[(long)n * 32 + f]) / (deg[n] + 1.0f);
        float v = fmaxf(acc0 + acc1 + self + bv, 0.f);
        B[(long)n * 32 + f] = __float2bfloat16(v);
        a1 += v; a2 += v * v;
    }
    s1[tid] = a1; s2[tid] = a2; __syncthreads();
    for (int st = 128; st >= 32; st >>= 1) {
        if (tid < st) { s1[tid] += s1[tid + st]; s2[tid] += s2[tid + st]; }
        __syncthreads();
    }
    if (tid < 32) { atomicAdd(&sum[f], s1[f]); atomicAdd(&sq[f], s2[f]); }
}

// ---- BN1 finalize ----------------------------------------------------------
__global__ void k_fin1(const float* __restrict__ sum, const float* __restrict__ sq,
                       const float* __restrict__ g, const float* __restrict__ be,
                       float* __restrict__ scale, float* __restrict__ shift) {
    int t = threadIdx.x;
    if (t < 32) {
        float mu = sum[t] / (float)N_NODES;
        float var = sq[t] / (float)N_NODES - mu * mu;
        float rs = rsqrtf(var + BN_EPS) * g[t];
        scale[t] = rs;
        shift[t] = be[t] - mu * rs;
    }
}

// ---- H = affine(B) (bf16); A = H @ W2 (bf16) -------------------------------
__global__ void k_aff_xw(const bf16* __restrict__ B, const float* __restrict__ scale,
                         const float* __restrict__ shift, const float* __restrict__ w,
                         bf16* __restrict__ H, bf16* __restrict__ A) {
    __shared__ float Ws[32 * 33];
    __shared__ float hs[256];
    for (int i = threadIdx.x; i < 1024; i += 256)
        Ws[(i >> 5) * 33 + (i & 31)] = w[i];
    long base = (long)blockIdx.x * 256;
    int f = threadIdx.x & 31;
    float h = b2f(B[base + threadIdx.x]) * scale[f] + shift[f];
    H[base + threadIdx.x] = __float2bfloat16(h);
    hs[threadIdx.x] = h;
    __syncthreads();
    int r = threadIdx.x >> 5, hc = threadIdx.x & 31;
    float acc = 0.f;
#pragma unroll
    for (int k = 0; k < 32; k++) acc += hs[r * 32 + k] * Ws[k * 33 + hc];
    A[base + threadIdx.x] = __float2bfloat16(acc);
}

// ---- BN2 finalize + fc1 const + combined LSTM biases -----------------------
__global__ void k_fin2(const float* __restrict__ sum, const float* __restrict__ sq,
                       const float* __restrict__ g, const float* __restrict__ be,
                       const float* __restrict__ xsum, const float* __restrict__ fw1,
                       const float* __restrict__ fb1,
                       const float* __restrict__ bih1, const float* __restrict__ bhh1,
                       const float* __restrict__ bih2, const float* __restrict__ bhh2,
                       float* __restrict__ scale, float* __restrict__ shift,
                       float* __restrict__ fc1c, float* __restrict__ lb1,
                       float* __restrict__ lb2) {
    int t = threadIdx.x;
    if (t < 32) {
        float mu = sum[t] / (float)N_NODES;
        float var = sq[t] / (float)N_NODES - mu * mu;
        float rs = rsqrtf(var + BN_EPS) * g[t];
        scale[t] = rs;
        shift[t] = be[t] - mu * rs;
        float c = fb1[t];
        for (int f = 0; f < 32; f++)
            c += (xsum[f] / (float)N_NODES) * fw1[t * 96 + 64 + f];
        fc1c[t] = c;
    }
    if (t < 128) {
        lb1[t] = bih1[t] + bhh1[t];
        lb2[t] = bih2[t] + bhh2[t];
    }
}

// ---- per-node dense stack: LDS-broadcast weights + v_pk_fma ---------------
__global__ __launch_bounds__(128) void k_final(
    const bf16* __restrict__ Hb, const bf16* __restrict__ Bb,
    const float* __restrict__ scale2, const float* __restrict__ shift2,
    const float* __restrict__ wih1, const float* __restrict__ wih2,
    const float* __restrict__ fw1, const float* __restrict__ fw2,
    const float* __restrict__ fb2,
    const float* __restrict__ fc1c, const float* __restrict__ lb1,
    const float* __restrict__ lb2, float* __restrict__ out) {
    __shared__ float4 Wa[1536];   // LSTM1: i rows 0..511, g 512..1023, o 1024..1535
    __shared__ float4 Wb[768];    // LSTM2: i/g/o, 8 float4 per row
    __shared__ float4 Fc[512];    // fc1 rows j: k 0..63 (16 float4)
    __shared__ float lb1s[128], lb2s[128], fc1s[32], fw2s[32], sc2[32], sh2[32];
    int tid = threadIdx.x;
    for (int i = tid; i < 1536; i += 128) {
        int t = i >> 9, rem = i & 511, c = rem >> 4, q = rem & 15;
        int row = (t == 0) ? c : ((t == 1) ? c + 64 : c + 96);
        Wa[i] = ((const float4*)(wih1 + row * 64))[q];
    }
    for (int i = tid; i < 768; i += 128) {
        int t = i / 256, rem = i % 256, c = rem >> 3, q = rem & 7;
        int row = (t == 0) ? c : ((t == 1) ? c + 64 : c + 96);
        Wb[i] = ((const float4*)(wih2 + row * 32))[q];
    }
    for (int i = tid; i < 512; i += 128) {
        int j = i >> 4, q = i & 15;
        Fc[i] = ((const float4*)(fw1 + j * 96))[q];
    }
    if (tid < 128) { lb1s[tid] = lb1[tid]; lb2s[tid] = lb2[tid]; }
    if (tid < 32) {
        fc1s[tid] = fc1c[tid]; fw2s[tid] = fw2[tid];
        sc2[tid] = scale2[tid]; sh2[tid] = shift2[tid];
    }
    __syncthreads();
    int n = blockIdx.x * 128 + tid;
    if (n >= N_NODES) return;

    v2f cat2[32];
    const uint4* Hv = (const uint4*)((const ushort*)Hb + (long)n * 32);
    const uint4* Bv = (const uint4*)((const ushort*)Bb + (long)n * 32);
#pragma unroll
    for (int q = 0; q < 4; q++) {
        uint4 hu = Hv[q], bu = Bv[q];
        uint hw[4] = {hu.x, hu.y, hu.z, hu.w};
        uint bw[4] = {bu.x, bu.y, bu.z, bu.w};
#pragma unroll
        for (int r = 0; r < 4; r++) {
            int u = q * 4 + r;
            float h0 = __uint_as_float(hw[r] << 16);
            float h1 = __uint_as_float(hw[r] & 0xffff0000u);
            cat2[u] = (v2f){h0, h1};
            float b0 = __uint_as_float(bw[r] << 16);
            float b1 = __uint_as_float(bw[r] & 0xffff0000u);
            int e0 = 2 * u, e1 = 2 * u + 1;
            cat2[16 + u] = (v2f){b0 * sc2[e0] + sh2[e0], b1 * sc2[e1] + sh2[e1]};
        }
    }
    v2f hn1v[16];
#pragma unroll
    for (int c = 0; c < 32; c++) {
        v2f ai = (v2f)0.f, ag = (v2f)0.f, ao = (v2f)0.f;
#pragma unroll
        for (int q = 0; q < 16; q++) {
            float4 wi = Wa[c * 16 + q], wg = Wa[512 + c * 16 + q], wo = Wa[1024 + c * 16 + q];
            v2f x0 = cat2[2 * q], x1 = cat2[2 * q + 1];
            ai = __builtin_elementwise_fma((v2f){wi.x, wi.y}, x0, ai);
            ai = __builtin_elementwise_fma((v2f){wi.z, wi.w}, x1, ai);
            ag = __builtin_elementwise_fma((v2f){wg.x, wg.y}, x0, ag);
            ag = __builtin_elementwise_fma((v2f){wg.z, wg.w}, x1, ag);
            ao = __builtin_elementwise_fma((v2f){wo.x, wo.y}, x0, ao);
            ao = __builtin_elementwise_fma((v2f){wo.z, wo.w}, x1, ao);
        }
        float gi = ai.x + ai.y + lb1s[c];
        float gg = ag.x + ag.y + lb1s[64 + c];
        float go = ao.x + ao.y + lb1s[96 + c];
        float c1 = fsig(gi) * ftanh(gg);
        hn1v[c >> 1][c & 1] = fsig(go) * ftanh(c1);
    }
    v2f hn2v[16];
#pragma unroll
    for (int c = 0; c < 32; c++) {
        v2f ai = (v2f)0.f, ag = (v2f)0.f, ao = (v2f)0.f;
#pragma unroll
        for (int q = 0; q < 8; q++) {
            float4 wi = Wb[c * 8 + q], wg = Wb[256 + c * 8 + q], wo = Wb[512 + c * 8 + q];
            v2f x0 = hn1v[2 * q], x1 = hn1v[2 * q + 1];
            ai = __builtin_elementwise_fma((v2f){wi.x, wi.y}, x0, ai);
            ai = __builtin_elementwise_fma((v2f){wi.z, wi.w}, x1, ai);
            ag = __builtin_elementwise_fma((v2f){wg.x, wg.y}, x0, ag);
            ag = __builtin_elementwise_fma((v2f){wg.z, wg.w}, x1, ag);
            ao = __builtin_elementwise_fma((v2f){wo.x, wo.y}, x0, ao);
            ao = __builtin_elementwise_fma((v2f){wo.z, wo.w}, x1, ao);
        }
        float gi = ai.x + ai.y + lb2s[c];
        float gg = ag.x + ag.y + lb2s[64 + c];
        float go = ao.x + ao.y + lb2s[96 + c];
        float c2 = fsig(gi) * ftanh(gg);
        hn2v[c >> 1][c & 1] = fsig(go) * ftanh(c2);
    }
    float acc = fb2[0];
#pragma unroll
    for (int j = 0; j < 32; j++) {
        v2f z2 = (v2f)0.f;
#pragma unroll
        for (int q = 0; q < 8; q++) {
            float4 w = Fc[j * 16 + q];
            z2 = __builtin_elementwise_fma((v2f){w.x, w.y}, hn1v[2 * q], z2);
            z2 = __builtin_elementwise_fma((v2f){w.z, w.w}, hn1v[2 * q + 1], z2);
        }
#pragma unroll
        for (int q = 0; q < 8; q++) {
            float4 w = Fc[j * 16 + 8 + q];
            z2 = __builtin_elementwise_fma((v2f){w.x, w.y}, hn2v[2 * q], z2);
            z2 = __builtin_elementwise_fma((v2f){w.z, w.w}, hn2v[2 * q + 1], z2);
        }
        float z = z2.x + z2.y + fc1s[j];
        acc += fmaxf(z, 0.f) * fw2s[j];
    }
    out[n] = acc;
}

extern "C" void kernel_launch(void* const* d_in, const int* in_sizes, int n_in,
                              void* d_out, int out_size, void* d_ws, size_t ws_size,
                              hipStream_t stream) {
    const float* x    = (const float*)d_in[0];
    const int*   ei   = (const int*)d_in[1];
    const float* ew   = (const float*)d_in[2];
    const float* w1   = (const float*)d_in[3];
    const float* b1   = (const float*)d_in[4];
    const float* g1   = (const float*)d_in[5];
    const float* be1  = (const float*)d_in[6];
    const float* w2   = (const float*)d_in[7];
    const float* b2   = (const float*)d_in[8];
    const float* g2   = (const float*)d_in[9];
    const float* be2  = (const float*)d_in[10];
    const float* wih1 = (const float*)d_in[11];
    const float* bih1 = (const float*)d_in[13];
    const float* bhh1 = (const float*)d_in[14];
    const float* wih2 = (const float*)d_in[15];
    const float* bih2 = (const float*)d_in[17];
    const float* bhh2 = (const float*)d_in[18];
    const float* fw1  = (const float*)d_in[19];
    const float* fb1  = (const float*)d_in[20];
    const float* fw2  = (const float*)d_in[21];
    const float* fb2  = (const float*)d_in[22];
    float* out = (float*)d_out;

    // ---- workspace layout (34.1 MB; known-good ws >= 41.1 MB) --------------
    // NOTE r6 bug: bsum/bbase (1564 B each) were at +2304/+3072 and overran
    // into deg at +4096 -> k_bscan clobbered deg[0..134]. Now in the free gap
    // after cnt (804,096..1,048,576); neither needs zero-init (write-first).
    char* ws = (char*)d_ws;
    float* stats = (float*)ws;                          // 576 floats @ 0
    float* xsum   = stats + 0;
    float* bn1sum = stats + 32;
    float* bn1sq  = stats + 64;
    float* bn2sum = stats + 96;
    float* bn2sq  = stats + 128;
    float* scale1 = stats + 160;
    float* shift1 = stats + 192;
    float* scale2 = stats + 224;
    float* shift2 = stats + 256;
    float* fc1c   = stats + 288;
    float* lb1    = stats + 320;
    float* lb2    = stats + 448;
    float* deg   = (float*)(ws + 4096);                 // 100000 f -> 404,096
    int*   cnt   = (int*)  (ws + 404096);               // 100000 i -> 804,096
    int*   bsum  = (int*)  (ws + 804096);               // 391 i -> 805,660
    int*   bbase = (int*)  (ws + 808192);               // 391 i -> 809,756
    int*   off   = (int*)  (ws + 1048576);              // 100001 i -> 1,448,580
    int*   cursor= (int*)  (ws + 1572864);              // 100000 i -> 1,972,864
    int2*  epk   = (int2*) (ws + 2097152);              // 1.6M int2 -> 14,897,152
    bf16*  A     = (bf16*) (ws + 14897152);             // 6.4MB -> 21,297,152
    bf16*  H     = (bf16*) (ws + 21297152);             // 6.4MB -> 27,697,152
    bf16*  B     = (bf16*) (ws + 27697152);             // 6.4MB -> 34,097,152

    if (ws_size < 34200000ull) {
        k_marker<<<(N_NODES + 255) / 256, 256, 0, stream>>>(out, N_NODES, 911.f);
        return;
    }

    // zero stats+deg+cnt in one shot (bytes 0 .. 804,096)
    k_zero_f<<<786, 256, 0, stream>>>(stats, 201024);

    k_hist<<<6250, 256, 0, stream>>>(ei, ew, cnt, deg);
    k_bsum<<<SCAN_BLOCKS, 256, 0, stream>>>(cnt, bsum);
    k_bscan<<<1, 512, 0, stream>>>(bsum, bbase);
    k_scan3<<<SCAN_BLOCKS, 256, 0, stream>>>(cnt, bbase, off, cursor);
    k_scatter<<<6250, 256, 0, stream>>>(ei, ew, deg, cursor, epk);
    k_xmean<<<400, 256, 0, stream>>>(x, xsum);
    k_xw1<<<12500, 256, 0, stream>>>(x, w1, A);
    k_gcn<<<1024, 256, 0, stream>>>(off, epk, A, deg, b1, B, bn1sum, bn1sq);
    k_fin1<<<1, 64, 0, stream>>>(bn1sum, bn1sq, g1, be1, scale1, shift1);
    k_aff_xw<<<12500, 256, 0, stream>>>(B, scale1, shift1, w2, H, A);
    k_gcn<<<1024, 256, 0, stream>>>(off, epk, A, deg, b2, B, bn2sum, bn2sq);
    k_fin2<<<1, 128, 0, stream>>>(bn2sum, bn2sq, g2, be2, xsum, fw1, fb1,
                                  bih1, bhh1, bih2, bhh2,
                                  scale2, shift2, fc1c, lb1, lb2);
    k_final<<<782, 128, 0, stream>>>(H, B, scale2, shift2, wih1, wih2, fw1, fw2,
                                     fb2, fc1c, lb1, lb2, out);
}

// Round 8
// 563.110 us; speedup vs baseline: 1.6590x; 1.2068x over previous
//
#include <hip/hip_runtime.h>
#include <hip/hip_bf16.h>

#define N_NODES 100000
#define N_EDGES 1600000
#define BN_EPS 1e-5f
#define SCAN_BLOCKS 391   // ceil(100000/256)

typedef __hip_bfloat16 bf16;
typedef unsigned long long ull;
typedef float v2f __attribute__((ext_vector_type(2)));

__device__ __forceinline__ float b2f(bf16 v) { return __bfloat162float(v); }
__device__ __forceinline__ float frcp(float x) { return __builtin_amdgcn_rcpf(x); }
__device__ __forceinline__ float fsig(float x) { return frcp(1.0f + __expf(-x)); }
__device__ __forceinline__ float ftanh(float x) {
    return 1.0f - 2.0f * frcp(__expf(2.0f * x) + 1.0f);
}
__device__ __forceinline__ float bfr(uint u) { return __uint_as_float(u << 16); }

// ---- utility ---------------------------------------------------------------
__global__ void k_zero_f(float* __restrict__ p, int n) {
    int i = blockIdx.x * 256 + threadIdx.x;
    if (i < n) p[i] = 0.f;
}
__global__ void k_marker(float* __restrict__ p, int n, float v) {
    int i = blockIdx.x * 256 + threadIdx.x;
    if (i < n) p[i] = v;
}

// ---- packed histogram: pk[d] += (1<<48)|fx(ew); rank = old count -----------
// count in bits 48..63 (max deg ~60 << 2^16), fixed-point sum(ew) in bits
// 0..47 (max 60*2^32 < 2^38, no carry into count). One atomic per edge,
// and its return value hands us the edge's unique rank within dst for free.
__global__ void k_hist(const int* __restrict__ ei, const float* __restrict__ ew,
                       ull* __restrict__ pk, int* __restrict__ rank) {
    int e = blockIdx.x * 256 + threadIdx.x;
    if (e < N_EDGES) {
        int d = ei[N_EDGES + e];
        ull v = (1ull << 48) | (ull)((double)ew[e] * 4294967296.0);
        ull old = atomicAdd(&pk[d], v);
        rank[e] = (int)(old >> 48);
    }
}

// ---- parallel scan, stage 1: per-block sums of counts ----------------------
__global__ void k_bsum(const ull* __restrict__ pk, int* __restrict__ bsum) {
    __shared__ int s[256];
    int idx = blockIdx.x * 256 + threadIdx.x;
    s[threadIdx.x] = (idx < N_NODES) ? (int)(pk[idx] >> 48) : 0;
    __syncthreads();
    for (int st = 128; st >= 1; st >>= 1) {
        if (threadIdx.x < st) s[threadIdx.x] += s[threadIdx.x + st];
        __syncthreads();
    }
    if (threadIdx.x == 0) bsum[blockIdx.x] = s[0];
}

// ---- stage 2: exclusive scan of 391 block sums (single tiny block) ---------
__global__ __launch_bounds__(512) void k_bscan(const int* __restrict__ bsum,
                                               int* __restrict__ bbase) {
    __shared__ int s[512];
    int t = threadIdx.x;
    int v = (t < SCAN_BLOCKS) ? bsum[t] : 0;
    s[t] = v; __syncthreads();
    for (int st = 1; st < 512; st <<= 1) {
        int u = (t >= st) ? s[t - st] : 0;
        __syncthreads();
        s[t] += u;
        __syncthreads();
    }
    if (t < SCAN_BLOCKS) bbase[t] = s[t] - v;   // exclusive prefix
}

// ---- stage 3: block scan -> off; unpack deg from pk ------------------------
__global__ void k_scan3(const ull* __restrict__ pk, const int* __restrict__ bbase,
                        int* __restrict__ off, float* __restrict__ deg) {
    __shared__ int wsum[4];
    int idx = blockIdx.x * 256 + threadIdx.x;
    int lane = threadIdx.x & 63, w = threadIdx.x >> 6;
    ull pv = (idx < N_NODES) ? pk[idx] : 0ull;
    int c = (int)(pv >> 48);
    int s = c;
    for (int d = 1; d < 64; d <<= 1) {
        int u = __shfl_up(s, d, 64);
        if (lane >= d) s += u;
    }
    if (lane == 63) wsum[w] = s;
    __syncthreads();
    int wb = 0;
    for (int i = 0; i < w; i++) wb += wsum[i];
    int e = bbase[blockIdx.x] + wb + s - c;      // exclusive
    if (idx < N_NODES) {
        off[idx] = e;
        deg[idx] = (float)((double)(pv & 0xFFFFFFFFFFFFull) * (1.0 / 4294967296.0));
    }
    if (idx == 0) off[N_NODES] = N_EDGES;        // all dst are in-range
}

// ---- scatter edges into CSR slots as {src, norm} — NO atomics --------------
__global__ void k_scatter(const int* __restrict__ ei, const float* __restrict__ ew,
                          const float* __restrict__ deg, const int* __restrict__ off,
                          const int* __restrict__ rank, int2* __restrict__ epk) {
    int e = blockIdx.x * 256 + threadIdx.x;
    if (e < N_EDGES) {
        int s = ei[e], d = ei[N_EDGES + e];
        float nm = ew[e] * rsqrtf((deg[s] + 1.0f) * (deg[d] + 1.0f));
        epk[off[d] + rank[e]] = make_int2(s, __float_as_int(nm));
    }
}

// ---- column sums of x (for skip_avg) ---------------------------------------
__global__ void k_xmean(const float* __restrict__ x, float* __restrict__ xsum) {
    __shared__ float s[256];
    int f = threadIdx.x & 31, rg = threadIdx.x >> 5;
    float acc = 0.f;
    for (int n = blockIdx.x * 8 + rg; n < N_NODES; n += gridDim.x * 8)
        acc += x[n * 32 + f];
    s[threadIdx.x] = acc; __syncthreads();
    for (int st = 128; st >= 32; st >>= 1) {
        if (threadIdx.x < st) s[threadIdx.x] += s[threadIdx.x + st];
        __syncthreads();
    }
    if (threadIdx.x < 32) atomicAdd(&xsum[threadIdx.x], s[threadIdx.x]);
}

// ---- A = x @ W1 (fp32 in, bf16 out) ----------------------------------------
__global__ void k_xw1(const float* __restrict__ x, const float* __restrict__ w,
                      bf16* __restrict__ A) {
    __shared__ float Ws[32 * 33];
    __shared__ float xs[256];
    for (int i = threadIdx.x; i < 1024; i += 256)
        Ws[(i >> 5) * 33 + (i & 31)] = w[i];
    long base = (long)blockIdx.x * 256;
    xs[threadIdx.x] = x[base + threadIdx.x];
    __syncthreads();
    int r = threadIdx.x >> 5, h = threadIdx.x & 31;
    float acc = 0.f;
#pragma unroll
    for (int f = 0; f < 32; f++) acc += xs[r * 32 + f] * Ws[f * 33 + h];
    A[base + threadIdx.x] = __float2bfloat16(acc);
}

// ---- pull-mode GCN: agg + self-loop + bias + relu + BN stats ---------------
__global__ __launch_bounds__(256) void k_gcn(
    const int* __restrict__ off, const int2* __restrict__ epk,
    const bf16* __restrict__ A, const float* __restrict__ deg,
    const float* __restrict__ bias, bf16* __restrict__ B,
    float* __restrict__ sum, float* __restrict__ sq) {
    __shared__ float s1[256], s2[256];
    const ushort* Au = (const ushort*)A;
    int tid = threadIdx.x, f = tid & 31, g = tid >> 5;
    float bv = bias[f];
    float a1 = 0.f, a2 = 0.f;
    for (int n = blockIdx.x * 8 + g; n < N_NODES; n += gridDim.x * 8) {
        int lo = off[n], hi = off[n + 1];
        float acc0 = 0.f, acc1 = 0.f;
        int p = lo;
        for (; p + 1 < hi; p += 2) {
            int2 e0 = epk[p], e1 = epk[p + 1];
            acc0 += bfr(Au[(long)e0.x * 32 + f]) * __int_as_float(e0.y);
            acc1 += bfr(Au[(long)e1.x * 32 + f]) * __int_as_float(e1.y);
        }
        if (p < hi) {
            int2 e0 = epk[p];
            acc0 += bfr(Au[(long)e0.x * 32 + f]) * __int_as_float(e0.y);
        }
        float self = bfr(Au[(long)n * 32 + f]) / (deg[n] + 1.0f);
        float v = fmaxf(acc0 + acc1 + self + bv, 0.f);
        B[(long)n * 32 + f] = __float2bfloat16(v);
        a1 += v; a2 += v * v;
    }
    s1[tid] = a1; s2[tid] = a2; __syncthreads();
    for (int st = 128; st >= 32; st >>= 1) {
        if (tid < st) { s1[tid] += s1[tid + st]; s2[tid] += s2[tid + st]; }
        __syncthreads();
    }
    if (tid < 32) { atomicAdd(&sum[f], s1[f]); atomicAdd(&sq[f], s2[f]); }
}

// ---- BN1 finalize ----------------------------------------------------------
__global__ void k_fin1(const float* __restrict__ sum, const float* __restrict__ sq,
                       const float* __restrict__ g, const float* __restrict__ be,
                       float* __restrict__ scale, float* __restrict__ shift) {
    int t = threadIdx.x;
    if (t < 32) {
        float mu = sum[t] / (float)N_NODES;
        float var = sq[t] / (float)N_NODES - mu * mu;
        float rs = rsqrtf(var + BN_EPS) * g[t];
        scale[t] = rs;
        shift[t] = be[t] - mu * rs;
    }
}

// ---- H = affine(B) (bf16); A = H @ W2 (bf16) -------------------------------
__global__ void k_aff_xw(const bf16* __restrict__ B, const float* __restrict__ scale,
                         const float* __restrict__ shift, const float* __restrict__ w,
                         bf16* __restrict__ H, bf16* __restrict__ A) {
    __shared__ float Ws[32 * 33];
    __shared__ float hs[256];
    for (int i = threadIdx.x; i < 1024; i += 256)
        Ws[(i >> 5) * 33 + (i & 31)] = w[i];
    long base = (long)blockIdx.x * 256;
    int f = threadIdx.x & 31;
    float h = b2f(B[base + threadIdx.x]) * scale[f] + shift[f];
    H[base + threadIdx.x] = __float2bfloat16(h);
    hs[threadIdx.x] = h;
    __syncthreads();
    int r = threadIdx.x >> 5, hc = threadIdx.x & 31;
    float acc = 0.f;
#pragma unroll
    for (int k = 0; k < 32; k++) acc += hs[r * 32 + k] * Ws[k * 33 + hc];
    A[base + threadIdx.x] = __float2bfloat16(acc);
}

// ---- BN2 finalize + fc1 const + combined LSTM biases -----------------------
__global__ void k_fin2(const float* __restrict__ sum, const float* __restrict__ sq,
                       const float* __restrict__ g, const float* __restrict__ be,
                       const float* __restrict__ xsum, const float* __restrict__ fw1,
                       const float* __restrict__ fb1,
                       const float* __restrict__ bih1, const float* __restrict__ bhh1,
                       const float* __restrict__ bih2, const float* __restrict__ bhh2,
                       float* __restrict__ scale, float* __restrict__ shift,
                       float* __restrict__ fc1c, float* __restrict__ lb1,
                       float* __restrict__ lb2) {
    int t = threadIdx.x;
    if (t < 32) {
        float mu = sum[t] / (float)N_NODES;
        float var = sq[t] / (float)N_NODES - mu * mu;
        float rs = rsqrtf(var + BN_EPS) * g[t];
        scale[t] = rs;
        shift[t] = be[t] - mu * rs;
        float c = fb1[t];
        for (int f = 0; f < 32; f++)
            c += (xsum[f] / (float)N_NODES) * fw1[t * 96 + 64 + f];
        fc1c[t] = c;
    }
    if (t < 128) {
        lb1[t] = bih1[t] + bhh1[t];
        lb2[t] = bih2[t] + bhh2[t];
    }
}

// ---- per-node dense stack: LDS-broadcast weights + v_pk_fma ---------------
__global__ __launch_bounds__(128) void k_final(
    const bf16* __restrict__ Hb, const bf16* __restrict__ Bb,
    const float* __restrict__ scale2, const float* __restrict__ shift2,
    const float* __restrict__ wih1, const float* __restrict__ wih2,
    const float* __restrict__ fw1, const float* __restrict__ fw2,
    const float* __restrict__ fb2,
    const float* __restrict__ fc1c, const float* __restrict__ lb1,
    const float* __restrict__ lb2, float* __restrict__ out) {
    __shared__ float4 Wa[1536];   // LSTM1: i rows 0..511, g 512..1023, o 1024..1535
    __shared__ float4 Wb[768];    // LSTM2: i/g/o, 8 float4 per row
    __shared__ float4 Fc[512];    // fc1 rows j: k 0..63 (16 float4)
    __shared__ float lb1s[128], lb2s[128], fc1s[32], fw2s[32], sc2[32], sh2[32];
    int tid = threadIdx.x;
    for (int i = tid; i < 1536; i += 128) {
        int t = i >> 9, rem = i & 511, c = rem >> 4, q = rem & 15;
        int row = (t == 0) ? c : ((t == 1) ? c + 64 : c + 96);
        Wa[i] = ((const float4*)(wih1 + row * 64))[q];
    }
    for (int i = tid; i < 768; i += 128) {
        int t = i / 256, rem = i % 256, c = rem >> 3, q = rem & 7;
        int row = (t == 0) ? c : ((t == 1) ? c + 64 : c + 96);
        Wb[i] = ((const float4*)(wih2 + row * 32))[q];
    }
    for (int i = tid; i < 512; i += 128) {
        int j = i >> 4, q = i & 15;
        Fc[i] = ((const float4*)(fw1 + j * 96))[q];
    }
    if (tid < 128) { lb1s[tid] = lb1[tid]; lb2s[tid] = lb2[tid]; }
    if (tid < 32) {
        fc1s[tid] = fc1c[tid]; fw2s[tid] = fw2[tid];
        sc2[tid] = scale2[tid]; sh2[tid] = shift2[tid];
    }
    __syncthreads();
    int n = blockIdx.x * 128 + tid;
    if (n >= N_NODES) return;

    v2f cat2[32];
    const uint4* Hv = (const uint4*)((const ushort*)Hb + (long)n * 32);
    const uint4* Bv = (const uint4*)((const ushort*)Bb + (long)n * 32);
#pragma unroll
    for (int q = 0; q < 4; q++) {
        uint4 hu = Hv[q], bu = Bv[q];
        uint hw[4] = {hu.x, hu.y, hu.z, hu.w};
        uint bw[4] = {bu.x, bu.y, bu.z, bu.w};
#pragma unroll
        for (int r = 0; r < 4; r++) {
            int u = q * 4 + r;
            float h0 = __uint_as_float(hw[r] << 16);
            float h1 = __uint_as_float(hw[r] & 0xffff0000u);
            cat2[u] = (v2f){h0, h1};
            float b0 = __uint_as_float(bw[r] << 16);
            float b1 = __uint_as_float(bw[r] & 0xffff0000u);
            int e0 = 2 * u, e1 = 2 * u + 1;
            cat2[16 + u] = (v2f){b0 * sc2[e0] + sh2[e0], b1 * sc2[e1] + sh2[e1]};
        }
    }
    v2f hn1v[16];
#pragma unroll
    for (int c = 0; c < 32; c++) {
        v2f ai = (v2f)0.f, ag = (v2f)0.f, ao = (v2f)0.f;
#pragma unroll
        for (int q = 0; q < 16; q++) {
            float4 wi = Wa[c * 16 + q], wg = Wa[512 + c * 16 + q], wo = Wa[1024 + c * 16 + q];
            v2f x0 = cat2[2 * q], x1 = cat2[2 * q + 1];
            ai = __builtin_elementwise_fma((v2f){wi.x, wi.y}, x0, ai);
            ai = __builtin_elementwise_fma((v2f){wi.z, wi.w}, x1, ai);
            ag = __builtin_elementwise_fma((v2f){wg.x, wg.y}, x0, ag);
            ag = __builtin_elementwise_fma((v2f){wg.z, wg.w}, x1, ag);
            ao = __builtin_elementwise_fma((v2f){wo.x, wo.y}, x0, ao);
            ao = __builtin_elementwise_fma((v2f){wo.z, wo.w}, x1, ao);
        }
        float gi = ai.x + ai.y + lb1s[c];
        float gg = ag.x + ag.y + lb1s[64 + c];
        float go = ao.x + ao.y + lb1s[96 + c];
        float c1 = fsig(gi) * ftanh(gg);
        hn1v[c >> 1][c & 1] = fsig(go) * ftanh(c1);
    }
    v2f hn2v[16];
#pragma unroll
    for (int c = 0; c < 32; c++) {
        v2f ai = (v2f)0.f, ag = (v2f)0.f, ao = (v2f)0.f;
#pragma unroll
        for (int q = 0; q < 8; q++) {
            float4 wi = Wb[c * 8 + q], wg = Wb[256 + c * 8 + q], wo = Wb[512 + c * 8 + q];
            v2f x0 = hn1v[2 * q], x1 = hn1v[2 * q + 1];
            ai = __builtin_elementwise_fma((v2f){wi.x, wi.y}, x0, ai);
            ai = __builtin_elementwise_fma((v2f){wi.z, wi.w}, x1, ai);
            ag = __builtin_elementwise_fma((v2f){wg.x, wg.y}, x0, ag);
            ag = __builtin_elementwise_fma((v2f){wg.z, wg.w}, x1, ag);
            ao = __builtin_elementwise_fma((v2f){wo.x, wo.y}, x0, ao);
            ao = __builtin_elementwise_fma((v2f){wo.z, wo.w}, x1, ao);
        }
        float gi = ai.x + ai.y + lb2s[c];
        float gg = ag.x + ag.y + lb2s[64 + c];
        float go = ao.x + ao.y + lb2s[96 + c];
        float c2 = fsig(gi) * ftanh(gg);
        hn2v[c >> 1][c & 1] = fsig(go) * ftanh(c2);
    }
    float acc = fb2[0];
#pragma unroll
    for (int j = 0; j < 32; j++) {
        v2f z2 = (v2f)0.f;
#pragma unroll
        for (int q = 0; q < 8; q++) {
            float4 w = Fc[j * 16 + q];
            z2 = __builtin_elementwise_fma((v2f){w.x, w.y}, hn1v[2 * q], z2);
            z2 = __builtin_elementwise_fma((v2f){w.z, w.w}, hn1v[2 * q + 1], z2);
        }
#pragma unroll
        for (int q = 0; q < 8; q++) {
            float4 w = Fc[j * 16 + 8 + q];
            z2 = __builtin_elementwise_fma((v2f){w.x, w.y}, hn2v[2 * q], z2);
            z2 = __builtin_elementwise_fma((v2f){w.z, w.w}, hn2v[2 * q + 1], z2);
        }
        float z = z2.x + z2.y + fc1s[j];
        acc += fmaxf(z, 0.f) * fw2s[j];
    }
    out[n] = acc;
}

extern "C" void kernel_launch(void* const* d_in, const int* in_sizes, int n_in,
                              void* d_out, int out_size, void* d_ws, size_t ws_size,
                              hipStream_t stream) {
    const float* x    = (const float*)d_in[0];
    const int*   ei   = (const int*)d_in[1];
    const float* ew   = (const float*)d_in[2];
    const float* w1   = (const float*)d_in[3];
    const float* b1   = (const float*)d_in[4];
    const float* g1   = (const float*)d_in[5];
    const float* be1  = (const float*)d_in[6];
    const float* w2   = (const float*)d_in[7];
    const float* b2   = (const float*)d_in[8];
    const float* g2   = (const float*)d_in[9];
    const float* be2  = (const float*)d_in[10];
    const float* wih1 = (const float*)d_in[11];
    const float* bih1 = (const float*)d_in[13];
    const float* bhh1 = (const float*)d_in[14];
    const float* wih2 = (const float*)d_in[15];
    const float* bih2 = (const float*)d_in[17];
    const float* bhh2 = (const float*)d_in[18];
    const float* fw1  = (const float*)d_in[19];
    const float* fb1  = (const float*)d_in[20];
    const float* fw2  = (const float*)d_in[21];
    const float* fb2  = (const float*)d_in[22];
    float* out = (float*)d_out;

    // ---- workspace layout (40.5 MB; proven ws >= 41.1 MB from r3/r4) -------
    char* ws = (char*)d_ws;
    float* stats = (float*)ws;                          // 576 floats @ 0
    float* xsum   = stats + 0;
    float* bn1sum = stats + 32;
    float* bn1sq  = stats + 64;
    float* bn2sum = stats + 96;
    float* bn2sq  = stats + 128;
    float* scale1 = stats + 160;
    float* shift1 = stats + 192;
    float* scale2 = stats + 224;
    float* shift2 = stats + 256;
    float* fc1c   = stats + 288;
    float* lb1    = stats + 320;
    float* lb2    = stats + 448;
    ull*   pk    = (ull*)  (ws + 4096);                 // 100000 ull -> 804,096
    int*   bsum  = (int*)  (ws + 804096);               // 391 i
    int*   bbase = (int*)  (ws + 808192);               // 391 i
    int*   off   = (int*)  (ws + 1048576);              // 100001 i -> 1,448,580
    float* deg   = (float*)(ws + 1572864);              // 100000 f -> 1,972,864
    int2*  epk   = (int2*) (ws + 2097152);              // 1.6M int2 -> 14,897,152
    int*   rank  = (int*)  (ws + 14897152);             // 1.6M i -> 21,297,152
    bf16*  A     = (bf16*) (ws + 21297152);             // 6.4MB -> 27,697,152
    bf16*  H     = (bf16*) (ws + 27697152);             // 6.4MB -> 34,097,152
    bf16*  B     = (bf16*) (ws + 34097152);             // 6.4MB -> 40,497,152

    if (ws_size < 40497152ull) {
        k_marker<<<(N_NODES + 255) / 256, 256, 0, stream>>>(out, N_NODES, 911.f);
        return;
    }

    // zero stats + pk in one shot (bytes 0 .. 804,096)
    k_zero_f<<<786, 256, 0, stream>>>(stats, 201024);

    k_hist<<<6250, 256, 0, stream>>>(ei, ew, pk, rank);
    k_bsum<<<SCAN_BLOCKS, 256, 0, stream>>>(pk, bsum);
    k_bscan<<<1, 512, 0, stream>>>(bsum, bbase);
    k_scan3<<<SCAN_BLOCKS, 256, 0, stream>>>(pk, bbase, off, deg);
    k_scatter<<<6250, 256, 0, stream>>>(ei, ew, deg, off, rank, epk);
    k_xmean<<<400, 256, 0, stream>>>(x, xsum);
    k_xw1<<<12500, 256, 0, stream>>>(x, w1, A);
    k_gcn<<<1024, 256, 0, stream>>>(off, epk, A, deg, b1, B, bn1sum, bn1sq);
    k_fin1<<<1, 64, 0, stream>>>(bn1sum, bn1sq, g1, be1, scale1, shift1);
    k_aff_xw<<<12500, 256, 0, stream>>>(B, scale1, shift1, w2, H, A);
    k_gcn<<<1024, 256, 0, stream>>>(off, epk, A, deg, b2, B, bn2sum, bn2sq);
    k_fin2<<<1, 128, 0, stream>>>(bn2sum, bn2sq, g2, be2, xsum, fw1, fb1,
                                  bih1, bhh1, bih2, bhh2,
                                  scale2, shift2, fc1c, lb1, lb2);
    k_final<<<782, 128, 0, stream>>>(H, B, scale2, shift2, wih1, wih2, fw1, fw2,
                                     fb2, fc1c, lb1, lb2, out);
}